// Round 18
// baseline (185.888 us; speedup 1.0000x reference)
//
#include <hip/hip_runtime.h>
#include <hip/hip_bf16.h>
#include <cstdint>

typedef __bf16 bf16x8 __attribute__((ext_vector_type(8)));
typedef __bf16 bf16x4 __attribute__((ext_vector_type(4)));
typedef float  f32x4  __attribute__((ext_vector_type(4)));
typedef float  f32x16 __attribute__((ext_vector_type(16)));
typedef unsigned u32x4 __attribute__((ext_vector_type(4)));

__device__ __forceinline__ f32x4 mfma16(bf16x8 a, bf16x8 b, f32x4 c) {
  return __builtin_amdgcn_mfma_f32_16x16x32_bf16(a, b, c, 0, 0, 0);
}
__device__ __forceinline__ f32x16 mfma32(bf16x8 a, bf16x8 b, f32x16 c) {
  return __builtin_amdgcn_mfma_f32_32x32x16_bf16(a, b, c, 0, 0, 0);
}

__device__ __forceinline__ void gload_lds16(const __bf16* g, __bf16* l) {
  __builtin_amdgcn_global_load_lds(
      (const __attribute__((address_space(1))) void*)g,
      (__attribute__((address_space(3))) void*)l, 16, 0, 0);
}

__device__ __forceinline__ unsigned cvtpk(float lo, float hi) {
  unsigned r;
  asm("v_cvt_pk_bf16_f32 %0, %1, %2" : "=v"(r) : "v"(lo), "v"(hi));
  return r;
}
// lane<32 halves swap between a and b
__device__ __forceinline__ void plswap(unsigned& a, unsigned& b) {
  asm("v_permlane32_swap_b32 %0, %1" : "+v"(a), "+v"(b));
}

// ---------------- fp32 -> bf16 convert (x4 per thread) ----------------
__global__ __launch_bounds__(256) void cvt_bf16_kernel(const float* __restrict__ in,
                                                       __bf16* __restrict__ out, int n4) {
  int i = blockIdx.x * 256 + threadIdx.x;
  if (i < n4) {
    float4 v = ((const float4*)in)[i];
    bf16x4 o;
    o[0] = (__bf16)v.x; o[1] = (__bf16)v.y; o[2] = (__bf16)v.z; o[3] = (__bf16)v.w;
    ((bf16x4*)out)[i] = o;
  }
}

// ------------- transpose + cvt: src (R x C) f32 -> dst (C x R) bf16 -------------
__global__ __launch_bounds__(256) void transpose_cvt_kernel(const float* __restrict__ src,
                                                            __bf16* __restrict__ dst,
                                                            int R, int C) {
  __shared__ float tile[32][33];
  int r0 = blockIdx.y * 32, c0 = blockIdx.x * 32;
  int tx = threadIdx.x & 31, ty = threadIdx.x >> 5;
#pragma unroll
  for (int i = 0; i < 4; ++i)
    tile[ty + i * 8][tx] = src[(size_t)(r0 + ty + i * 8) * C + c0 + tx];
  __syncthreads();
#pragma unroll
  for (int i = 0; i < 4; ++i) {
    int rr = ty + i * 8;
    dst[(size_t)(c0 + rr) * R + r0 + tx] = (__bf16)tile[tx][rr];
  }
}

// ------- bf16 GEMM v8: 256x256 tile, 512 thr (8 waves 2Mx4N, wave 128x64),
// BK=64, plain dbuf-2 (128KB LDS), stage(j+1) issued at iteration TOP (right
// after __syncthreads) -> issue-to-wait distance = 1 full tile (~2400cy) covers
// HBM latency; slot (j+1)&1's readers all passed the barrier (liveness clean).
// Wave-tile 128x64 gives 2.67 MFMA per ds_read_b128 (2x v7) — attacks the
// measured LDS read-issue wall (192 reads/tile ≈ 2260cy vs 621cy MFMA).
// Conflict-free frag pattern (16-row groups, ch=(p*4+(l>>4))^(row&7)), both-
// sides swizzle. Epilogue: v-third packs bf16x4. 1-D grid, XCD swizzle.
template <int EPI>
__global__ __launch_bounds__(512) void gemm_bt8_kernel(
    const __bf16* __restrict__ A, const __bf16* __restrict__ Bt,
    int M, int N, int K, int nbx,
    const float* __restrict__ bias,
    float* __restrict__ outF,
    __bf16* __restrict__ qo, __bf16* __restrict__ ko, __bf16* __restrict__ vTo) {
  __shared__ __attribute__((aligned(16))) __bf16 lA[2][256 * 64];  // 64KB
  __shared__ __attribute__((aligned(16))) __bf16 lB[2][256 * 64];  // 64KB
  const int t = threadIdx.x;
  const int l = t & 63, w = t >> 6;
  const int wm = (w >> 2) * 128, wn = (w & 3) * 64;
  const int cpx = gridDim.x >> 3;
  const int wg = (blockIdx.x & 7) * cpx + (blockIdx.x >> 3);
  const int m0 = (wg / nbx) * 256, n0 = (wg % nbx) * 256;
  const int nk = K >> 6;  // 12

  // 8 loads/thread/tile (4 A + 4 B); global src pre-swizzled (^row&7 chunk)
  auto stage = [&](int buf, int kt) {
    const __bf16* As = A + (size_t)m0 * K + kt * 64;
    const __bf16* Bs = Bt + (size_t)n0 * K + kt * 64;
#pragma unroll
    for (int r2 = 0; r2 < 4; ++r2) {
      int li = r2 * 512 + t;
      int row = li >> 3, pc = li & 7, lc = pc ^ (row & 7);
      gload_lds16(As + (size_t)row * K + lc * 8, &lA[buf][li * 8]);
      gload_lds16(Bs + (size_t)row * K + lc * 8, &lB[buf][li * 8]);
    }
  };

  f32x4 acc[8][4] = {};
  stage(0, 0);

  for (int j = 0; j < nk; ++j) {
    __syncthreads();                    // tile j resident (issued 1 full tile ago)
    if (j + 1 < nk) stage((j + 1) & 1, j + 1);  // issue EARLY: covered by this tile
    const __bf16* la = &lA[j & 1][0];
    const __bf16* lb = &lB[j & 1][0];
#pragma unroll
    for (int p = 0; p < 2; ++p) {
      bf16x8 af[8], bfv[4];
#pragma unroll
      for (int mt = 0; mt < 8; ++mt) {
        int row = wm + mt * 16 + (l & 15);
        int ch = (p * 4 + (l >> 4)) ^ (row & 7);
        af[mt] = *(const bf16x8*)(la + row * 64 + ch * 8);
      }
#pragma unroll
      for (int nt = 0; nt < 4; ++nt) {
        int row = wn + nt * 16 + (l & 15);
        int ch = (p * 4 + (l >> 4)) ^ (row & 7);
        bfv[nt] = *(const bf16x8*)(lb + row * 64 + ch * 8);
      }
      __builtin_amdgcn_s_setprio(1);
#pragma unroll
      for (int mt = 0; mt < 8; ++mt)
#pragma unroll
        for (int nt = 0; nt < 4; ++nt)
          acc[mt][nt] = mfma16(af[mt], bfv[nt], acc[mt][nt]);
      __builtin_amdgcn_s_setprio(0);
    }
  }

#pragma unroll
  for (int mt = 0; mt < 8; ++mt) {
#pragma unroll
    for (int nt = 0; nt < 4; ++nt) {
      int col = n0 + wn + nt * 16 + (l & 15);
      int row0 = m0 + wm + mt * 16 + (l >> 4) * 4;
      if constexpr (EPI == 0) {
        int s = col / 768, rem = col - s * 768;
        int h = rem >> 6, c = rem & 63;
        int b = row0 >> 9, n = row0 & 511;   // r=0..3 stay in same 512-block
        size_t bh = (size_t)(b * 12 + h);
        if (s == 2) {
          bf16x4 pv;
#pragma unroll
          for (int r = 0; r < 4; ++r) pv[r] = (__bf16)(acc[mt][nt][r] + bias[col]);
          *(bf16x4*)(vTo + (bh * 64 + c) * 512 + n) = pv;
        } else {
          __bf16* dst = (s == 0 ? qo : ko) + (bh * 512 + n) * 64 + c;
#pragma unroll
          for (int r = 0; r < 4; ++r) dst[(size_t)r * 64] = (__bf16)(acc[mt][nt][r] + bias[col]);
        }
      } else {
#pragma unroll
        for (int r = 0; r < 4; ++r)
          outF[(size_t)(row0 + r) * N + col] = acc[mt][nt][r] + bias[col];
      }
    }
  }
}

// ------------- fused attention (R16-validated): MFMA bias, in-reg P, ring-3 K/V -------------
__device__ __forceinline__ const bf16x8* kfrag(const __bf16* base, int row, int ch) {
  return (const bf16x8*)(base + row * 64 + ((ch ^ (row & 7)) * 8));
}
__device__ __forceinline__ const bf16x8* vfrag(const __bf16* base, int row, int ch) {
  return (const bf16x8*)(base + row * 32 + ((ch ^ ((row >> 1) & 3)) * 8));
}

__global__ __launch_bounds__(256, 4) void attn_kernel(
    const __bf16* __restrict__ qg_, const __bf16* __restrict__ kg,
    const __bf16* __restrict__ vT,
    const float* __restrict__ rpd, const float* __restrict__ rph,
    const float* __restrict__ rpw,
    __bf16* __restrict__ attn_out) {
  // XCD swizzle: 1536 blocks = 8 x 192
  const int bid = (blockIdx.x & 7) * 192 + (blockIdx.x >> 3);
  const int bh = bid >> 2;
  const int qb = bid & 3;
  const int t = threadIdx.x, w = t >> 6, l = t & 63;
  const int lq = l & 31, lh5 = l >> 5;

  __shared__ float bias_lds[128][25];
  __shared__ float rs_lds[4][32];
  __shared__ __attribute__((aligned(16))) __bf16 k_lds[3][32 * 64];
  __shared__ __attribute__((aligned(16))) __bf16 v_lds[3][64 * 32];

  const __bf16* kb = kg + (size_t)bh * 512 * 64;
  const __bf16* vb = vT + (size_t)bh * 64 * 512;

  auto stage = [&](int sbuf, int j0) {
    {
      int row = t >> 3, pc = t & 7;
      int lc = pc ^ (row & 7);
      gload_lds16(kb + (size_t)(j0 + row) * 64 + lc * 8, &k_lds[sbuf][t * 8]);
    }
    {
      int row = t >> 2, pc = t & 3;
      int lc = pc ^ ((row >> 1) & 3);
      gload_lds16(vb + (size_t)row * 512 + j0 + lc * 8, &v_lds[sbuf][t * 8]);
    }
  };

  stage(0, 0);    // tile 0
  stage(1, 32);   // tile 1

  const __bf16* qbase = qg_ + ((size_t)bh * 512 + qb * 128 + w * 32) * 64;
  bf16x8 qf[4];
#pragma unroll
  for (int s = 0; s < 4; ++s)
    qf[s] = *(const bf16x8*)(qbase + lq * 64 + s * 16 + lh5 * 8);

  // ---- bias precompute via MFMA (R10-validated) ----
  {
    const int row = w * 32 + lq;
    const int n = qb * 128 + row;
    const int dd = n >> 6, hh = (n >> 3) & 7, ww = n & 7;
#pragma unroll
    for (int jt = 0; jt < 2; ++jt) {
      const float* src;
      if (jt == 0) src = (lq < 15) ? rpd + (size_t)lq * 64
                                   : (lq >= 16 && lq < 31) ? rph + (size_t)(lq - 16) * 64
                                                           : nullptr;
      else         src = (lq < 15) ? rpw + (size_t)lq * 64 : nullptr;
      f32x16 cb = {};
#pragma unroll
      for (int s = 0; s < 4; ++s) {
        bf16x8 afr;
        if (src) {
          float4 a = *(const float4*)(src + s * 16 + lh5 * 8);
          float4 b = *(const float4*)(src + s * 16 + lh5 * 8 + 4);
          u32x4 u = {cvtpk(a.x, a.y), cvtpk(a.z, a.w), cvtpk(b.x, b.y), cvtpk(b.z, b.w)};
          afr = __builtin_bit_cast(bf16x8, u);
        } else {
          afr = bf16x8{};
        }
        cb = mfma32(afr, qf[s], cb);
      }
#pragma unroll
      for (int r = 0; r < 16; ++r) {
        int j = (r & 3) + 8 * (r >> 2) + 4 * lh5;
        if (jt == 0) {
          if (j < 16) {
            int idx = dd + 7 - j;
            if (idx >= 0 && idx < 8) bias_lds[row][idx] = cb[r];
          } else {
            int idx = hh + 7 - (j - 16);
            if (idx >= 0 && idx < 8) bias_lds[row][8 + idx] = cb[r];
          }
        } else {
          if (j < 16) {
            int idx = ww + 7 - j;
            if (idx >= 0 && idx < 8) bias_lds[row][16 + idx] = cb[r];
          }
        }
      }
    }
  }

  __syncthreads();  // tiles 0,1 drained (vmcnt ledger = 0 at loop entry); bias ready

  const float LOG2E = 1.44269504f;
  const float* brow = &bias_lds[w * 32 + lq][0];
  float bh2e[4], bh2o[4], bw2[4];
#pragma unroll
  for (int rr = 0; rr < 4; ++rr) {
    bh2e[rr] = brow[8 + rr] * LOG2E;
    bh2o[rr] = brow[12 + rr] * LOG2E;
    bw2[rr] = brow[16 + rr + 4 * lh5] * LOG2E;
  }

  f32x16 accO0 = {}, accO1 = {};
  float rs4[4] = {0.f, 0.f, 0.f, 0.f};
  const float scale2 = 0.125f * LOG2E;

  for (int kk = 0; kk < 8; ++kk) {
#pragma unroll
    for (int par = 0; par < 2; ++par) {
      const int kb_i = kk * 2 + par;
      asm volatile("s_waitcnt vmcnt(2)" ::: "memory");
      __builtin_amdgcn_s_barrier();
      __builtin_amdgcn_sched_barrier(0);
      const __bf16* kl = k_lds[kb_i % 3];
      const __bf16* vl = v_lds[kb_i % 3];
      const int st = (kb_i + 2 < 16) ? kb_i + 2 : kb_i;
      const int sb = (kb_i + 2) % 3;

      f32x16 accS = {};
#pragma unroll
      for (int s = 0; s < 4; ++s)
        accS = mfma32(*kfrag(kl, lq, lh5 + 2 * s), qf[s], accS);

      stage(sb, st * 32);

      float bd2 = brow[kb_i >> 1] * LOG2E;
      float pr[16];
#pragma unroll
      for (int rr = 0; rr < 4; ++rr) {
        float bsum = bd2 + (par ? bh2o[rr] : bh2e[rr]);
#pragma unroll
        for (int c = 0; c < 4; ++c) {
          int r = rr * 4 + c;
          float p = __builtin_amdgcn_exp2f(accS[r] * scale2 + bsum + bw2[c]);
          rs4[rr] += p;
          pr[r] = p;
        }
      }

      unsigned a0 = cvtpk(pr[0], pr[1]),   b0 = cvtpk(pr[4], pr[5]);
      unsigned a1 = cvtpk(pr[2], pr[3]),   b1 = cvtpk(pr[6], pr[7]);
      unsigned a2 = cvtpk(pr[8], pr[9]),   b2 = cvtpk(pr[12], pr[13]);
      unsigned a3 = cvtpk(pr[10], pr[11]), b3 = cvtpk(pr[14], pr[15]);
      plswap(a0, b0); plswap(a1, b1); plswap(a2, b2); plswap(a3, b3);
      u32x4 u0 = {a0, a1, b0, b1};
      u32x4 u1 = {a2, a3, b2, b3};
      bf16x8 pf0 = __builtin_bit_cast(bf16x8, u0);
      bf16x8 pf1 = __builtin_bit_cast(bf16x8, u1);

      __builtin_amdgcn_s_setprio(1);
      accO0 = mfma32(pf0, *vfrag(vl, lq, lh5), accO0);
      accO0 = mfma32(pf1, *vfrag(vl, lq, lh5 + 2), accO0);
      accO1 = mfma32(pf0, *vfrag(vl, 32 + lq, lh5), accO1);
      accO1 = mfma32(pf1, *vfrag(vl, 32 + lq, lh5 + 2), accO1);
      __builtin_amdgcn_s_setprio(0);
    }
  }

  {
    float rsum = (rs4[0] + rs4[1]) + (rs4[2] + rs4[3]);
    float s = rsum + __shfl_xor(rsum, 32);
    if (l < 32) rs_lds[w][l] = 1.f / s;
  }

  const int b_ = bh / 12, h_ = bh - b_ * 12;
  __bf16* obase = attn_out + ((size_t)b_ * 512 + qb * 128 + w * 32) * 768 + h_ * 64;
#pragma unroll
  for (int rr = 0; rr < 4; ++rr) {
#pragma unroll
    for (int c = 0; c < 4; ++c) {
      int r = rr * 4 + c;
      int qrow = c + 8 * rr + 4 * lh5;
      float inv = rs_lds[w][qrow];
      obase[(size_t)qrow * 768 + lq]      = (__bf16)(accO0[r] * inv);
      obase[(size_t)qrow * 768 + 32 + lq] = (__bf16)(accO1[r] * inv);
    }
  }
}

extern "C" void kernel_launch(void* const* d_in, const int* in_sizes, int n_in,
                              void* d_out, int out_size, void* d_ws, size_t ws_size,
                              hipStream_t stream) {
  const float* x      = (const float*)d_in[0];
  const float* w_qkv  = (const float*)d_in[1];
  const float* b_qkv  = (const float*)d_in[2];
  const float* w_proj = (const float*)d_in[3];
  const float* b_proj = (const float*)d_in[4];
  const float* rpd    = (const float*)d_in[5];
  const float* rph    = (const float*)d_in[6];
  const float* rpw    = (const float*)d_in[7];
  float* out = (float*)d_out;

  char* base = (char*)d_ws;
  __bf16* xb     = (__bf16*)(base);                                  // 16384x768 bf16; reused as attn_out
  __bf16* wqkvT  = (__bf16*)(base + 25165824);                       // 2304x768
  __bf16* wprojT = (__bf16*)(base + 25165824 + 3538944);             // 768x768
  __bf16* qb     = (__bf16*)(base + 25165824 + 3538944 + 1179648);   // 384x512x64
  __bf16* kb     = qb + (size_t)384 * 512 * 64;
  __bf16* vT     = kb + (size_t)384 * 512 * 64;

  cvt_bf16_kernel<<<12288, 256, 0, stream>>>(x, xb, 12582912 / 4);
  transpose_cvt_kernel<<<dim3(2304 / 32, 768 / 32), 256, 0, stream>>>(w_qkv, wqkvT, 768, 2304);
  transpose_cvt_kernel<<<dim3(768 / 32, 768 / 32), 256, 0, stream>>>(w_proj, wprojT, 768, 768);

  gemm_bt8_kernel<0><<<576, 512, 0, stream>>>(
      xb, wqkvT, 16384, 2304, 768, 9, b_qkv, nullptr, qb, kb, vT);

  attn_kernel<<<1536, 256, 0, stream>>>(qb, kb, vT, rpd, rph, rpw, xb);

  gemm_bt8_kernel<1><<<192, 512, 0, stream>>>(
      xb, wprojT, 16384, 768, 768, 3, b_proj, out, nullptr, nullptr, nullptr);
}

// Round 19
// 172.504 us; speedup vs baseline: 1.0776x; 1.0776x over previous
//
#include <hip/hip_runtime.h>
#include <hip/hip_bf16.h>
#include <cstdint>

typedef __bf16 bf16x8 __attribute__((ext_vector_type(8)));
typedef __bf16 bf16x4 __attribute__((ext_vector_type(4)));
typedef float  f32x4  __attribute__((ext_vector_type(4)));
typedef float  f32x16 __attribute__((ext_vector_type(16)));
typedef unsigned u32x4 __attribute__((ext_vector_type(4)));

__device__ __forceinline__ f32x4 mfma16(bf16x8 a, bf16x8 b, f32x4 c) {
  return __builtin_amdgcn_mfma_f32_16x16x32_bf16(a, b, c, 0, 0, 0);
}
__device__ __forceinline__ f32x16 mfma32(bf16x8 a, bf16x8 b, f32x16 c) {
  return __builtin_amdgcn_mfma_f32_32x32x16_bf16(a, b, c, 0, 0, 0);
}

__device__ __forceinline__ void gload_lds16(const __bf16* g, __bf16* l) {
  __builtin_amdgcn_global_load_lds(
      (const __attribute__((address_space(1))) void*)g,
      (__attribute__((address_space(3))) void*)l, 16, 0, 0);
}

__device__ __forceinline__ unsigned cvtpk(float lo, float hi) {
  unsigned r;
  asm("v_cvt_pk_bf16_f32 %0, %1, %2" : "=v"(r) : "v"(lo), "v"(hi));
  return r;
}
// lane<32 halves swap between a and b
__device__ __forceinline__ void plswap(unsigned& a, unsigned& b) {
  asm("v_permlane32_swap_b32 %0, %1" : "+v"(a), "+v"(b));
}

// ---------------- fp32 -> bf16 convert (x4 per thread) ----------------
__global__ __launch_bounds__(256) void cvt_bf16_kernel(const float* __restrict__ in,
                                                       __bf16* __restrict__ out, int n4) {
  int i = blockIdx.x * 256 + threadIdx.x;
  if (i < n4) {
    float4 v = ((const float4*)in)[i];
    bf16x4 o;
    o[0] = (__bf16)v.x; o[1] = (__bf16)v.y; o[2] = (__bf16)v.z; o[3] = (__bf16)v.w;
    ((bf16x4*)out)[i] = o;
  }
}

// ------------- transpose + cvt: src (R x C) f32 -> dst (C x R) bf16 -------------
__global__ __launch_bounds__(256) void transpose_cvt_kernel(const float* __restrict__ src,
                                                            __bf16* __restrict__ dst,
                                                            int R, int C) {
  __shared__ float tile[32][33];
  int r0 = blockIdx.y * 32, c0 = blockIdx.x * 32;
  int tx = threadIdx.x & 31, ty = threadIdx.x >> 5;
#pragma unroll
  for (int i = 0; i < 4; ++i)
    tile[ty + i * 8][tx] = src[(size_t)(r0 + ty + i * 8) * C + c0 + tx];
  __syncthreads();
#pragma unroll
  for (int i = 0; i < 4; ++i) {
    int rr = ty + i * 8;
    dst[(size_t)(c0 + rr) * R + r0 + tx] = (__bf16)tile[tx][rr];
  }
}

// ------- bf16 GEMM (R16-validated): BM=256 BN=128 BK=64, 512 thr (8 waves 4Mx2N),
// 3-stage LDS ring (144KB), counted vmcnt(6) — tile j+2 staged DURING iter j into
// buf[(j+2)%3] (dead since iter j-1; top barrier fences). 2 phases/iter, each:
// {8 ds_read_b128 (swz ^row&7, pre-swizzled global src) | 3-load stage slice |
//  setprio(1) 16 MFMA setprio(0)}. Never vmcnt(0) in loop. 1-D grid, XCD swizzle.
// Epilogue: v-third packs 4 consecutive-n values into one bf16x4 store.
template <int EPI>
__global__ __launch_bounds__(512) void gemm_bt3_kernel(
    const __bf16* __restrict__ A, const __bf16* __restrict__ Bt,
    int M, int N, int K, int nbx,
    const float* __restrict__ bias,
    float* __restrict__ outF,
    __bf16* __restrict__ qo, __bf16* __restrict__ ko, __bf16* __restrict__ vTo) {
  __shared__ __attribute__((aligned(16))) __bf16 lA[3][256 * 64];  // 96KB
  __shared__ __attribute__((aligned(16))) __bf16 lB[3][128 * 64];  // 48KB
  const int t = threadIdx.x;
  const int l = t & 63, w = t >> 6;
  const int wm = (w >> 1) * 64, wn = (w & 1) * 64;
  const int cpx = gridDim.x >> 3;
  const int wg = (blockIdx.x & 7) * cpx + (blockIdx.x >> 3);
  const int m0 = (wg / nbx) * 256, n0 = (wg % nbx) * 128;
  const int nk = K >> 6;  // 12

  auto stage = [&](int buf, int kt, int part) {
    const __bf16* As = A + (size_t)m0 * K + kt * 64;
    const __bf16* Bs = Bt + (size_t)n0 * K + kt * 64;
#pragma unroll
    for (int r2 = 0; r2 < 2; ++r2) {
      int li = (part * 2 + r2) * 512 + t;
      int row = li >> 3, pc = li & 7, lc = pc ^ (row & 7);
      gload_lds16(As + (size_t)row * K + lc * 8, &lA[buf][li * 8]);
    }
    {
      int li = part * 512 + t;
      int row = li >> 3, pc = li & 7, lc = pc ^ (row & 7);
      gload_lds16(Bs + (size_t)row * K + lc * 8, &lB[buf][li * 8]);
    }
  };

  f32x4 acc[4][4] = {};
  stage(0, 0, 0); stage(0, 0, 1);
  stage(1, 1, 0); stage(1, 1, 1);

  for (int j = 0; j < nk; ++j) {
    asm volatile("s_waitcnt vmcnt(6)" ::: "memory");   // tile j resident; j+1 in flight
    __builtin_amdgcn_s_barrier();
    __builtin_amdgcn_sched_barrier(0);
    const __bf16* la = &lA[j % 3][0];
    const __bf16* lb = &lB[j % 3][0];
    const int st = (j + 2 < nk) ? j + 2 : j;           // tail: dummy re-stage
    const int sb = (j + 2) % 3;
#pragma unroll
    for (int p = 0; p < 2; ++p) {
      bf16x8 af[4], bfv[4];
#pragma unroll
      for (int mt = 0; mt < 4; ++mt) {
        int row = wm + mt * 16 + (l & 15);
        int ch = (p * 4 + (l >> 4)) ^ (row & 7);
        af[mt] = *(const bf16x8*)(la + row * 64 + ch * 8);
      }
#pragma unroll
      for (int nt = 0; nt < 4; ++nt) {
        int row = wn + nt * 16 + (l & 15);
        int ch = (p * 4 + (l >> 4)) ^ (row & 7);
        bfv[nt] = *(const bf16x8*)(lb + row * 64 + ch * 8);
      }
      stage(sb, st, p);
      __builtin_amdgcn_s_setprio(1);
#pragma unroll
      for (int mt = 0; mt < 4; ++mt)
#pragma unroll
        for (int nt = 0; nt < 4; ++nt)
          acc[mt][nt] = mfma16(af[mt], bfv[nt], acc[mt][nt]);
      __builtin_amdgcn_s_setprio(0);
    }
  }

#pragma unroll
  for (int mt = 0; mt < 4; ++mt) {
#pragma unroll
    for (int nt = 0; nt < 4; ++nt) {
      int col = n0 + wn + nt * 16 + (l & 15);
      int row0 = m0 + wm + mt * 16 + (l >> 4) * 4;
      if constexpr (EPI == 0) {
        int s = col / 768, rem = col - s * 768;
        int h = rem >> 6, c = rem & 63;
        int b = row0 >> 9, n = row0 & 511;   // r=0..3 stay in same 512-block (row0 % 4 == 0)
        size_t bh = (size_t)(b * 12 + h);
        if (s == 2) {
          bf16x4 pv;
#pragma unroll
          for (int r = 0; r < 4; ++r) pv[r] = (__bf16)(acc[mt][nt][r] + bias[col]);
          *(bf16x4*)(vTo + (bh * 64 + c) * 512 + n) = pv;   // 4 consecutive n, 8B aligned
        } else {
          __bf16* dst = (s == 0 ? qo : ko) + (bh * 512 + n) * 64 + c;
#pragma unroll
          for (int r = 0; r < 4; ++r) dst[(size_t)r * 64] = (__bf16)(acc[mt][nt][r] + bias[col]);
        }
      } else {
#pragma unroll
        for (int r = 0; r < 4; ++r)
          outF[(size_t)(row0 + r) * N + col] = acc[mt][nt][r] + bias[col];
      }
    }
  }
}

// ------------- fused attention: MFMA bias, in-reg P, ring-3 counted-vmcnt K/V -------------
__device__ __forceinline__ const bf16x8* kfrag(const __bf16* base, int row, int ch) {
  return (const bf16x8*)(base + row * 64 + ((ch ^ (row & 7)) * 8));
}
__device__ __forceinline__ const bf16x8* vfrag(const __bf16* base, int row, int ch) {
  return (const bf16x8*)(base + row * 32 + ((ch ^ ((row >> 1) & 3)) * 8));
}

__global__ __launch_bounds__(256, 4) void attn_kernel(
    const __bf16* __restrict__ qg_, const __bf16* __restrict__ kg,
    const __bf16* __restrict__ vT,
    const float* __restrict__ rpd, const float* __restrict__ rph,
    const float* __restrict__ rpw,
    __bf16* __restrict__ attn_out) {
  // XCD swizzle: 1536 blocks = 8 x 192
  const int bid = (blockIdx.x & 7) * 192 + (blockIdx.x >> 3);
  const int bh = bid >> 2;
  const int qb = bid & 3;
  const int t = threadIdx.x, w = t >> 6, l = t & 63;
  const int lq = l & 31, lh5 = l >> 5;

  __shared__ float bias_lds[128][25];
  __shared__ float rs_lds[4][32];
  __shared__ __attribute__((aligned(16))) __bf16 k_lds[3][32 * 64];
  __shared__ __attribute__((aligned(16))) __bf16 v_lds[3][64 * 32];

  const __bf16* kb = kg + (size_t)bh * 512 * 64;
  const __bf16* vb = vT + (size_t)bh * 64 * 512;

  auto stage = [&](int sbuf, int j0) {
    {
      int row = t >> 3, pc = t & 7;
      int lc = pc ^ (row & 7);
      gload_lds16(kb + (size_t)(j0 + row) * 64 + lc * 8, &k_lds[sbuf][t * 8]);
    }
    {
      int row = t >> 2, pc = t & 3;
      int lc = pc ^ ((row >> 1) & 3);
      gload_lds16(vb + (size_t)row * 512 + j0 + lc * 8, &v_lds[sbuf][t * 8]);
    }
  };

  stage(0, 0);    // tile 0
  stage(1, 32);   // tile 1

  const __bf16* qbase = qg_ + ((size_t)bh * 512 + qb * 128 + w * 32) * 64;
  bf16x8 qf[4];
#pragma unroll
  for (int s = 0; s < 4; ++s)
    qf[s] = *(const bf16x8*)(qbase + lq * 64 + s * 16 + lh5 * 8);

  // ---- bias precompute via MFMA (R10-validated) ----
  {
    const int row = w * 32 + lq;
    const int n = qb * 128 + row;
    const int dd = n >> 6, hh = (n >> 3) & 7, ww = n & 7;
#pragma unroll
    for (int jt = 0; jt < 2; ++jt) {
      const float* src;
      if (jt == 0) src = (lq < 15) ? rpd + (size_t)lq * 64
                                   : (lq >= 16 && lq < 31) ? rph + (size_t)(lq - 16) * 64
                                                           : nullptr;
      else         src = (lq < 15) ? rpw + (size_t)lq * 64 : nullptr;
      f32x16 cb = {};
#pragma unroll
      for (int s = 0; s < 4; ++s) {
        bf16x8 afr;
        if (src) {
          float4 a = *(const float4*)(src + s * 16 + lh5 * 8);
          float4 b = *(const float4*)(src + s * 16 + lh5 * 8 + 4);
          u32x4 u = {cvtpk(a.x, a.y), cvtpk(a.z, a.w), cvtpk(b.x, b.y), cvtpk(b.z, b.w)};
          afr = __builtin_bit_cast(bf16x8, u);
        } else {
          afr = bf16x8{};
        }
        cb = mfma32(afr, qf[s], cb);
      }
#pragma unroll
      for (int r = 0; r < 16; ++r) {
        int j = (r & 3) + 8 * (r >> 2) + 4 * lh5;
        if (jt == 0) {
          if (j < 16) {
            int idx = dd + 7 - j;
            if (idx >= 0 && idx < 8) bias_lds[row][idx] = cb[r];
          } else {
            int idx = hh + 7 - (j - 16);
            if (idx >= 0 && idx < 8) bias_lds[row][8 + idx] = cb[r];
          }
        } else {
          if (j < 16) {
            int idx = ww + 7 - j;
            if (idx >= 0 && idx < 8) bias_lds[row][16 + idx] = cb[r];
          }
        }
      }
    }
  }

  __syncthreads();  // tiles 0,1 drained (vmcnt ledger = 0 at loop entry); bias ready

  const float LOG2E = 1.44269504f;
  const float* brow = &bias_lds[w * 32 + lq][0];
  float bh2e[4], bh2o[4], bw2[4];
#pragma unroll
  for (int rr = 0; rr < 4; ++rr) {
    bh2e[rr] = brow[8 + rr] * LOG2E;
    bh2o[rr] = brow[12 + rr] * LOG2E;
    bw2[rr] = brow[16 + rr + 4 * lh5] * LOG2E;
  }

  f32x16 accO0 = {}, accO1 = {};
  float rs4[4] = {0.f, 0.f, 0.f, 0.f};
  const float scale2 = 0.125f * LOG2E;

  for (int kk = 0; kk < 8; ++kk) {
#pragma unroll
    for (int par = 0; par < 2; ++par) {
      const int kb_i = kk * 2 + par;
      asm volatile("s_waitcnt vmcnt(2)" ::: "memory");
      __builtin_amdgcn_s_barrier();
      __builtin_amdgcn_sched_barrier(0);
      const __bf16* kl = k_lds[kb_i % 3];
      const __bf16* vl = v_lds[kb_i % 3];
      const int st = (kb_i + 2 < 16) ? kb_i + 2 : kb_i;
      const int sb = (kb_i + 2) % 3;

      f32x16 accS = {};
#pragma unroll
      for (int s = 0; s < 4; ++s)
        accS = mfma32(*kfrag(kl, lq, lh5 + 2 * s), qf[s], accS);

      stage(sb, st * 32);

      float bd2 = brow[kb_i >> 1] * LOG2E;
      float pr[16];
#pragma unroll
      for (int rr = 0; rr < 4; ++rr) {
        float bsum = bd2 + (par ? bh2o[rr] : bh2e[rr]);
#pragma unroll
        for (int c = 0; c < 4; ++c) {
          int r = rr * 4 + c;
          float p = __builtin_amdgcn_exp2f(accS[r] * scale2 + bsum + bw2[c]);
          rs4[rr] += p;
          pr[r] = p;
        }
      }

      unsigned a0 = cvtpk(pr[0], pr[1]),   b0 = cvtpk(pr[4], pr[5]);
      unsigned a1 = cvtpk(pr[2], pr[3]),   b1 = cvtpk(pr[6], pr[7]);
      unsigned a2 = cvtpk(pr[8], pr[9]),   b2 = cvtpk(pr[12], pr[13]);
      unsigned a3 = cvtpk(pr[10], pr[11]), b3 = cvtpk(pr[14], pr[15]);
      plswap(a0, b0); plswap(a1, b1); plswap(a2, b2); plswap(a3, b3);
      u32x4 u0 = {a0, a1, b0, b1};
      u32x4 u1 = {a2, a3, b2, b3};
      bf16x8 pf0 = __builtin_bit_cast(bf16x8, u0);
      bf16x8 pf1 = __builtin_bit_cast(bf16x8, u1);

      __builtin_amdgcn_s_setprio(1);
      accO0 = mfma32(pf0, *vfrag(vl, lq, lh5), accO0);
      accO0 = mfma32(pf1, *vfrag(vl, lq, lh5 + 2), accO0);
      accO1 = mfma32(pf0, *vfrag(vl, 32 + lq, lh5), accO1);
      accO1 = mfma32(pf1, *vfrag(vl, 32 + lq, lh5 + 2), accO1);
      __builtin_amdgcn_s_setprio(0);
    }
  }

  {
    float rsum = (rs4[0] + rs4[1]) + (rs4[2] + rs4[3]);
    float s = rsum + __shfl_xor(rsum, 32);
    if (l < 32) rs_lds[w][l] = 1.f / s;
  }

  const int b_ = bh / 12, h_ = bh - b_ * 12;
  __bf16* obase = attn_out + ((size_t)b_ * 512 + qb * 128 + w * 32) * 768 + h_ * 64;
#pragma unroll
  for (int rr = 0; rr < 4; ++rr) {
#pragma unroll
    for (int c = 0; c < 4; ++c) {
      int r = rr * 4 + c;
      int qrow = c + 8 * rr + 4 * lh5;
      float inv = rs_lds[w][qrow];
      obase[(size_t)qrow * 768 + lq]      = (__bf16)(accO0[r] * inv);
      obase[(size_t)qrow * 768 + 32 + lq] = (__bf16)(accO1[r] * inv);
    }
  }
}

extern "C" void kernel_launch(void* const* d_in, const int* in_sizes, int n_in,
                              void* d_out, int out_size, void* d_ws, size_t ws_size,
                              hipStream_t stream) {
  const float* x      = (const float*)d_in[0];
  const float* w_qkv  = (const float*)d_in[1];
  const float* b_qkv  = (const float*)d_in[2];
  const float* w_proj = (const float*)d_in[3];
  const float* b_proj = (const float*)d_in[4];
  const float* rpd    = (const float*)d_in[5];
  const float* rph    = (const float*)d_in[6];
  const float* rpw    = (const float*)d_in[7];
  float* out = (float*)d_out;

  char* base = (char*)d_ws;
  __bf16* xb     = (__bf16*)(base);                                  // 16384x768 bf16; reused as attn_out
  __bf16* wqkvT  = (__bf16*)(base + 25165824);                       // 2304x768
  __bf16* wprojT = (__bf16*)(base + 25165824 + 3538944);             // 768x768
  __bf16* qb     = (__bf16*)(base + 25165824 + 3538944 + 1179648);   // 384x512x64
  __bf16* kb     = qb + (size_t)384 * 512 * 64;
  __bf16* vT     = kb + (size_t)384 * 512 * 64;

  cvt_bf16_kernel<<<12288, 256, 0, stream>>>(x, xb, 12582912 / 4);
  transpose_cvt_kernel<<<dim3(2304 / 32, 768 / 32), 256, 0, stream>>>(w_qkv, wqkvT, 768, 2304);
  transpose_cvt_kernel<<<dim3(768 / 32, 768 / 32), 256, 0, stream>>>(w_proj, wprojT, 768, 768);

  gemm_bt3_kernel<0><<<1152, 512, 0, stream>>>(
      xb, wqkvT, 16384, 2304, 768, 18, b_qkv, nullptr, qb, kb, vT);

  attn_kernel<<<1536, 256, 0, stream>>>(qb, kb, vT, rpd, rph, rpw, xb);

  gemm_bt3_kernel<1><<<384, 512, 0, stream>>>(
      xb, wprojT, 16384, 768, 768, 6, b_proj, out, nullptr, nullptr, nullptr);
}